// Round 5
// baseline (2300.031 us; speedup 1.0000x reference)
//
#include <hip/hip_runtime.h>
#include <math.h>

#define N_M 100000
#define N_E 50000
#define FM 256
#define FE 64
#define H 128
#define NEDGE 1000000
#define NLBL 250000

#define BUCK 128                       // dst nodes per bucket
#define NB_M ((N_M + BUCK - 1) / BUCK) // 782
#define NB_E ((N_E + BUCK - 1) / BUCK) // 391
#define CAP_M 2048                     // >> mean 1280 (+21 sigma)
#define CAP_E 4096                     // >> mean 2560 (+30 sigma)
#define CHUNK 8192

typedef unsigned short u16;
typedef unsigned int u32;
typedef short bf16x8 __attribute__((ext_vector_type(8)));
typedef float f32x4  __attribute__((ext_vector_type(4)));
typedef u16 u16x8    __attribute__((ext_vector_type(8)));
typedef u16 u16x4    __attribute__((ext_vector_type(4)));

__device__ __forceinline__ u16 f2bf(float x) {
    unsigned u = __float_as_uint(x);
    u += 0x7FFF + ((u >> 16) & 1);           // RNE
    return (u16)(u >> 16);
}
__device__ __forceinline__ float bf2f(u16 h) {
    return __uint_as_float(((unsigned)h) << 16);
}

// ---------------------------------------------------------------------------
// Weight packing into mfma_f32_16x16x32_bf16 B-fragment order.
// ---------------------------------------------------------------------------
#define NPACK 14
struct PackDesc { const float* src; u16* dst; int K, N; };
struct PackArgs { PackDesc d[NPACK]; };

__global__ __launch_bounds__(64)
void pack_kernel(PackArgs args)
{
    PackDesc pd = args.d[blockIdx.y];
    int KT = pd.K / 32, NT = pd.N / 16;
    int tile = blockIdx.x;
    if (tile >= KT * NT) return;
    int kt = tile / NT, nt = tile % NT;
    int l = threadIdx.x;
    u16* dst = pd.dst + ((size_t)tile * 64 + l) * 8;
    #pragma unroll
    for (int j = 0; j < 8; ++j) {
        float v = pd.src[(size_t)(kt * 32 + (l >> 4) * 8 + j) * pd.N + nt * 16 + (l & 15)];
        dst[j] = f2bf(v);
    }
}

// ---------------------------------------------------------------------------
// MFMA GEMM: C[M,N](bf16) = act( A1@W1 [+ A2@W2] [+ bias] )
// ---------------------------------------------------------------------------
template<int K, int N, bool HAS_A2, bool RELU, bool A_FP32, bool HAS_BIAS>
__global__ __launch_bounds__(256)
void mfma_gemm(const void* __restrict__ A1, const void* __restrict__ A2,
               const u16* __restrict__ W1p, const u16* __restrict__ W2p,
               const float* __restrict__ bias, u16* __restrict__ C, int M)
{
    constexpr int NT = N / 16, KT = K / 32;
    const int wid = threadIdx.x >> 6, lane = threadIdx.x & 63;
    const int row0 = blockIdx.x * 64 + wid * 16;
    if (row0 >= M) return;
    const int l15 = lane & 15, l4 = lane >> 4;

    f32x4 acc[NT];
    #pragma unroll
    for (int nt = 0; nt < NT; ++nt) acc[nt] = (f32x4){0.f, 0.f, 0.f, 0.f};

    const int npass = HAS_A2 ? 2 : 1;
    for (int pass = 0; pass < npass; ++pass) {
        const void* A = pass ? A2 : A1;
        const u16* Wp = pass ? W2p : W1p;
        #pragma unroll
        for (int kt = 0; kt < KT; ++kt) {
            bf16x8 a;
            if constexpr (A_FP32) {
                const float* ap = (const float*)A + (size_t)(row0 + l15) * K + kt * 32 + l4 * 8;
                float4 f0 = *(const float4*)ap;
                float4 f1 = *(const float4*)(ap + 4);
                a[0] = (short)f2bf(f0.x); a[1] = (short)f2bf(f0.y);
                a[2] = (short)f2bf(f0.z); a[3] = (short)f2bf(f0.w);
                a[4] = (short)f2bf(f1.x); a[5] = (short)f2bf(f1.y);
                a[6] = (short)f2bf(f1.z); a[7] = (short)f2bf(f1.w);
            } else {
                a = *(const bf16x8*)((const u16*)A + (size_t)(row0 + l15) * K + kt * 32 + l4 * 8);
            }
            #pragma unroll
            for (int nt = 0; nt < NT; ++nt) {
                bf16x8 b = *(const bf16x8*)(Wp + ((size_t)(kt * NT + nt) * 64 + lane) * 8);
                acc[nt] = __builtin_amdgcn_mfma_f32_16x16x32_bf16(a, b, acc[nt], 0, 0, 0);
            }
        }
    }

    #pragma unroll
    for (int nt = 0; nt < NT; ++nt) {
        #pragma unroll
        for (int r = 0; r < 4; ++r) {
            int row = row0 + l4 * 4 + r;
            int col = nt * 16 + l15;
            float v = acc[nt][r];
            if (HAS_BIAS) v += bias[col];
            if (RELU) v = fmaxf(v, 0.f);
            C[(size_t)row * N + col] = f2bf(v);
        }
    }
}

// ---------------------------------------------------------------------------
// Phase A: LDS-staged bucketing of edges by dst bucket (BUCK nodes each).
// Each block bins CHUNK edges in LDS, then copies each bucket's segment out
// CONTIGUOUSLY after one atomic reservation per (block,bucket) — sequential
// chunk writes, no cacheline write amplification.
// Payload: packed u32 = (dst_local << 24) | src   (src < 2^17).
// ---------------------------------------------------------------------------
template<int NB, int CAP>
__global__ __launch_bounds__(512)
void bucket_kernel(const int* __restrict__ src, const int* __restrict__ dst,
                   u32* __restrict__ pairs, int* __restrict__ gcur)
{
    __shared__ u32 stag[CHUNK];     // 32 KB
    __shared__ int cnt[1024];       // padded for scan
    __shared__ int base[1024];
    __shared__ int sc[512];
    __shared__ int cursor[NB];

    const int tid = threadIdx.x;
    const int e0 = blockIdx.x * CHUNK;
    const int e1 = min(e0 + CHUNK, NEDGE);

    cnt[tid] = 0; cnt[tid + 512] = 0;
    __syncthreads();
    for (int e = e0 + tid; e < e1; e += 512)
        atomicAdd(&cnt[dst[e] / BUCK], 1);
    __syncthreads();

    // exclusive scan of cnt[0..1023]: each thread owns slots 2t, 2t+1
    int a0 = cnt[2 * tid], a1 = cnt[2 * tid + 1];
    int ts = a0 + a1;
    sc[tid] = ts;
    __syncthreads();
    for (int off = 1; off < 512; off <<= 1) {
        int v = (tid >= off) ? sc[tid - off] : 0;
        __syncthreads();
        sc[tid] += v;
        __syncthreads();
    }
    int excl = sc[tid] - ts;
    base[2 * tid] = excl;
    base[2 * tid + 1] = excl + a0;
    if (2 * tid < NB)     cursor[2 * tid] = excl;
    if (2 * tid + 1 < NB) cursor[2 * tid + 1] = excl + a0;
    __syncthreads();

    for (int e = e0 + tid; e < e1; e += 512) {
        int d = dst[e];
        int b = d / BUCK;
        u32 pk = ((u32)(d - b * BUCK) << 24) | (u32)src[e];
        int p = atomicAdd(&cursor[b], 1);
        stag[p] = pk;
    }
    __syncthreads();

    // copy out: wave w handles buckets w, w+8, ...
    const int wid = tid >> 6, lane = tid & 63;
    for (int b = wid; b < NB; b += 8) {
        int c = cnt[b];
        if (c == 0) continue;
        int gb = 0;
        if (lane == 0) gb = atomicAdd(&gcur[b], c);
        gb = __shfl(gb, 0);
        int lb = base[b];
        for (int i = lane; i < c; i += 64) {
            int idx = gb + i;
            if (idx < CAP) pairs[(size_t)b * CAP + idx] = stag[lb + i];
        }
    }
}

// ---------------------------------------------------------------------------
// Phase B: fused gather + segment-mean. One block per bucket; 64 KB fp32
// accumulator in LDS; edges unsorted within bucket -> ds_add_f32.
// ---------------------------------------------------------------------------
template<int CAP>
__global__ __launch_bounds__(512)
void bucket_mean_kernel(const u16* __restrict__ z,
                        const u32* __restrict__ pairs, const int* __restrict__ gcur,
                        u16* __restrict__ outm, int n_nodes)
{
    __shared__ float accum[BUCK * H];   // 64 KB
    __shared__ int cntS[BUCK];

    const int tid = threadIdx.x;
    const int b = blockIdx.x;
    const int g0 = b * BUCK;

    for (int i = tid; i < BUCK * H / 4; i += 512)
        ((float4*)accum)[i] = (float4){0.f, 0.f, 0.f, 0.f};
    if (tid < BUCK) cntS[tid] = 0;
    __syncthreads();

    const int n = min(gcur[b], CAP);
    const u32* pb = pairs + (size_t)b * CAP;
    const int grp = tid >> 5, lane = tid & 31;
    for (int e = grp; e < n; e += 16) {
        u32 pk = pb[e];
        int s = pk & 0xFFFFFF;
        int loc = pk >> 24;
        u16x4 v = *(const u16x4*)&z[(size_t)s * H + lane * 4];
        float* ap = &accum[loc * H + lane * 4];
        atomicAdd(ap + 0, bf2f(v[0]));
        atomicAdd(ap + 1, bf2f(v[1]));
        atomicAdd(ap + 2, bf2f(v[2]));
        atomicAdd(ap + 3, bf2f(v[3]));
        if (lane == 0) atomicAdd(&cntS[loc], 1);
    }
    __syncthreads();

    // write means: thread t -> node t>>2, channels (t&3)*32 .. +31
    const int node = tid >> 2, q = tid & 3;
    if (g0 + node < n_nodes) {
        float inv = 1.0f / fmaxf((float)cntS[node], 1.0f);
        const float* ap = &accum[node * H + q * 32];
        u16* op = &outm[(size_t)(g0 + node) * H + q * 32];
        #pragma unroll
        for (int c = 0; c < 32; c += 8) {
            u16x8 o;
            #pragma unroll
            for (int j = 0; j < 8; ++j) o[j] = f2bf(ap[c + j] * inv);
            *(u16x8*)&op[c] = o;
        }
    }
}

// ---------------------------------------------------------------------------
// Edge decode: out[e] = sigmoid( relu(Us[s] + Ud[d] + b1) . W2 + b2 )
// ---------------------------------------------------------------------------
#define EPQ 8
#define NQ  31250   // NLBL / EPQ

__global__ __launch_bounds__(256)
void edge_decode_kernel(const u16* __restrict__ Us, const u16* __restrict__ Ud,
                        const int* __restrict__ lsrc, const int* __restrict__ ldst,
                        const float* __restrict__ b1, const float* __restrict__ W2,
                        const float* __restrict__ b2, float* __restrict__ out)
{
    const int t  = blockIdx.x * 256 + threadIdx.x;
    const int q  = t >> 4;
    const int li = t & 15;
    if (q >= NQ) return;

    float w2v[16], b1v[16];
    #pragma unroll
    for (int j = 0; j < 4; ++j) {
        float4 w = *(const float4*)&W2[li * 16 + j * 4];
        float4 bb = *(const float4*)&b1[li * 16 + j * 4];
        w2v[j*4+0] = w.x; w2v[j*4+1] = w.y; w2v[j*4+2] = w.z; w2v[j*4+3] = w.w;
        b1v[j*4+0] = bb.x; b1v[j*4+1] = bb.y; b1v[j*4+2] = bb.z; b1v[j*4+3] = bb.w;
    }
    const float bout = b2[0];

    #pragma unroll
    for (int i = 0; i < EPQ; ++i) {
        int e = q + i * NQ;
        int s = lsrc[e], d = ldst[e];
        const u16* us = Us + (size_t)s * 256 + li * 16;
        const u16* ud = Ud + (size_t)d * 256 + li * 16;
        u16x8 sa = *(const u16x8*)us;
        u16x8 sb = *(const u16x8*)(us + 8);
        u16x8 da = *(const u16x8*)ud;
        u16x8 db = *(const u16x8*)(ud + 8);
        float acc = 0.f;
        #pragma unroll
        for (int j = 0; j < 8; ++j)
            acc += fmaxf(bf2f(sa[j]) + bf2f(da[j]) + b1v[j], 0.f) * w2v[j];
        #pragma unroll
        for (int j = 0; j < 8; ++j)
            acc += fmaxf(bf2f(sb[j]) + bf2f(db[j]) + b1v[8 + j], 0.f) * w2v[8 + j];
        acc += __shfl_xor(acc, 1, 16);
        acc += __shfl_xor(acc, 2, 16);
        acc += __shfl_xor(acc, 4, 16);
        acc += __shfl_xor(acc, 8, 16);
        if (li == 0) out[e] = 1.0f / (1.0f + expf(-(acc + bout)));
    }
}

// ---------------------------------------------------------------------------
extern "C" void kernel_launch(void* const* d_in, const int* in_sizes, int n_in,
                              void* d_out, int out_size, void* d_ws, size_t ws_size,
                              hipStream_t stream)
{
    const float* x_m      = (const float*)d_in[0];
    const float* x_e      = (const float*)d_in[1];
    const int*   src_m2e  = (const int*)d_in[2];
    const int*   dst_m2e  = (const int*)d_in[3];
    const int*   src_e2m  = (const int*)d_in[4];
    const int*   dst_e2m  = (const int*)d_in[5];
    const int*   lsrc_m2e = (const int*)d_in[6];
    const int*   ldst_m2e = (const int*)d_in[7];
    const int*   lsrc_e2m = (const int*)d_in[8];
    const int*   ldst_e2m = (const int*)d_in[9];
    const float* Wp_m   = (const float*)d_in[10];
    const float* bp_m   = (const float*)d_in[11];
    const float* Wp_e   = (const float*)d_in[12];
    const float* bp_e   = (const float*)d_in[13];
    const float* Wl_m2e = (const float*)d_in[14];
    const float* bl_m2e = (const float*)d_in[15];
    const float* Wr_m2e = (const float*)d_in[16];
    const float* Wl_e2m = (const float*)d_in[17];
    const float* bl_e2m = (const float*)d_in[18];
    const float* Wr_e2m = (const float*)d_in[19];
    const float* Wffw_m = (const float*)d_in[20];
    const float* bffw_m = (const float*)d_in[21];
    const float* Wffw_e = (const float*)d_in[22];
    const float* bffw_e = (const float*)d_in[23];
    const float* Wproj_m = (const float*)d_in[24];
    const float* bproj_m = (const float*)d_in[25];
    const float* Wproj_e = (const float*)d_in[26];
    const float* bproj_e = (const float*)d_in[27];
    const float* Wmlp_m2e = (const float*)d_in[28];
    const float* bmlp_m2e = (const float*)d_in[29];
    const float* Wout_m2e = (const float*)d_in[30];
    const float* bout_m2e = (const float*)d_in[31];
    const float* Wmlp_e2m = (const float*)d_in[32];
    const float* bmlp_e2m = (const float*)d_in[33];
    const float* Wout_e2m = (const float*)d_in[34];
    const float* bout_e2m = (const float*)d_in[35];

    float* out = (float*)d_out;

    // ---- workspace layout (u16 elems unless noted) ----
    u16* B_m = (u16*)d_ws;                       // mean_m -> h_m
    u16* B_e = B_m + (size_t)N_M * H;            // mean_e -> h_e
    u16* U0  = B_e + (size_t)N_E * H;            // 2*N_M*256 u16 region
    u16* A_m = U0;                               // z_m -> h_ffw_m
    u16* A_e = A_m + (size_t)N_M * H;
    u16* Us  = U0;                               // decoder precomputes (step 7+)
    u16* Ud  = U0 + (size_t)N_M * 256;
    // pairs/gcur overlay dead tail of U region (dead before Us/Ud written)
    u32* pairs_m = (u32*)(A_e + (size_t)N_E * H);
    u32* pairs_e = pairs_m + (size_t)NB_M * CAP_M;
    int* gcur_m  = (int*)(pairs_e + (size_t)NB_E * CAP_E);
    int* gcur_e  = gcur_m + NB_M;
    u16* pk = U0 + 2 * (size_t)N_M * 256;
    u16* pWp_m   = pk;  pk += 256 * 128;
    u16* pWp_e   = pk;  pk += 64 * 128;
    u16* pWl_e2m = pk;  pk += 128 * 128;
    u16* pWr_e2m = pk;  pk += 128 * 128;
    u16* pWl_m2e = pk;  pk += 128 * 128;
    u16* pWr_m2e = pk;  pk += 128 * 128;
    u16* pWffw_m = pk;  pk += 128 * 128;
    u16* pWffw_e = pk;  pk += 128 * 128;
    u16* pWproj_m= pk;  pk += 128 * 128;
    u16* pWproj_e= pk;  pk += 128 * 128;
    u16* pW1a_m2e= pk;  pk += 128 * 256;
    u16* pW1b_m2e= pk;  pk += 128 * 256;
    u16* pW1a_e2m= pk;  pk += 128 * 256;
    u16* pW1b_e2m= pk;  pk += 128 * 256;

    dim3 blk(256);
    dim3 gm((N_M + 63) / 64), ge((N_E + 63) / 64);

    // 0) pack all weights into MFMA B-frag layout
    PackArgs pa;
    pa.d[0]  = { Wp_m,               pWp_m,    FM, H };
    pa.d[1]  = { Wp_e,               pWp_e,    FE, H };
    pa.d[2]  = { Wl_e2m,             pWl_e2m,  H,  H };
    pa.d[3]  = { Wr_e2m,             pWr_e2m,  H,  H };
    pa.d[4]  = { Wl_m2e,             pWl_m2e,  H,  H };
    pa.d[5]  = { Wr_m2e,             pWr_m2e,  H,  H };
    pa.d[6]  = { Wffw_m,             pWffw_m,  H,  H };
    pa.d[7]  = { Wffw_e,             pWffw_e,  H,  H };
    pa.d[8]  = { Wproj_m,            pWproj_m, H,  H };
    pa.d[9]  = { Wproj_e,            pWproj_e, H,  H };
    pa.d[10] = { Wmlp_m2e,           pW1a_m2e, H,  256 };
    pa.d[11] = { Wmlp_m2e + 128*256, pW1b_m2e, H,  256 };
    pa.d[12] = { Wmlp_e2m,           pW1a_e2m, H,  256 };
    pa.d[13] = { Wmlp_e2m + 128*256, pW1b_e2m, H,  256 };
    pack_kernel<<<dim3(64, NPACK), dim3(64), 0, stream>>>(pa);

    // 1) input projections (fp32 A -> bf16 out)
    mfma_gemm<FM, H, false, false, true, true><<<gm, blk, 0, stream>>>(
        x_m, nullptr, pWp_m, nullptr, bp_m, A_m, N_M);
    mfma_gemm<FE, H, false, false, true, true><<<ge, blk, 0, stream>>>(
        x_e, nullptr, pWp_e, nullptr, bp_e, A_e, N_E);

    // 2) bucket edges by destination (LDS counting sort, contiguous writes)
    hipMemsetAsync(gcur_m, 0, sizeof(int) * (NB_M + NB_E), stream);
    const int nbk = (NEDGE + CHUNK - 1) / CHUNK;
    bucket_kernel<NB_M, CAP_M><<<dim3(nbk), dim3(512), 0, stream>>>(
        src_e2m, dst_e2m, pairs_m, gcur_m);
    bucket_kernel<NB_E, CAP_E><<<dim3(nbk), dim3(512), 0, stream>>>(
        src_m2e, dst_m2e, pairs_e, gcur_e);

    // 3) fused gather + segment mean (LDS accumulators, no global atomics)
    bucket_mean_kernel<CAP_M><<<dim3(NB_M), dim3(512), 0, stream>>>(
        A_e, pairs_m, gcur_m, B_m, N_M);
    bucket_mean_kernel<CAP_E><<<dim3(NB_E), dim3(512), 0, stream>>>(
        A_m, pairs_e, gcur_e, B_e, N_E);

    // 4) SAGE combine + relu (in place on B)
    mfma_gemm<H, H, true, true, false, true><<<gm, blk, 0, stream>>>(
        B_m, A_m, pWl_e2m, pWr_e2m, bl_e2m, B_m, N_M);
    mfma_gemm<H, H, true, true, false, true><<<ge, blk, 0, stream>>>(
        B_e, A_e, pWl_m2e, pWr_m2e, bl_m2e, B_e, N_E);

    // 5) ffw + relu: B -> A
    mfma_gemm<H, H, false, true, false, true><<<gm, blk, 0, stream>>>(
        B_m, nullptr, pWffw_m, nullptr, bffw_m, A_m, N_M);
    mfma_gemm<H, H, false, true, false, true><<<ge, blk, 0, stream>>>(
        B_e, nullptr, pWffw_e, nullptr, bffw_e, A_e, N_E);

    // 6) output projection: A -> B   (h_m in B_m, h_e in B_e)
    mfma_gemm<H, H, false, false, false, true><<<gm, blk, 0, stream>>>(
        A_m, nullptr, pWproj_m, nullptr, bproj_m, B_m, N_M);
    mfma_gemm<H, H, false, false, false, true><<<ge, blk, 0, stream>>>(
        A_e, nullptr, pWproj_e, nullptr, bproj_e, B_e, N_E);

    // 7) decoder m2e: U precompute (A/pairs region now dead) + edge decode
    dim3 gdq((NQ * 16 + 255) / 256);
    mfma_gemm<H, 256, false, false, false, false><<<gm, blk, 0, stream>>>(
        B_m, nullptr, pW1a_m2e, nullptr, nullptr, Us, N_M);
    mfma_gemm<H, 256, false, false, false, false><<<ge, blk, 0, stream>>>(
        B_e, nullptr, pW1b_m2e, nullptr, nullptr, Ud, N_E);
    edge_decode_kernel<<<gdq, blk, 0, stream>>>(
        Us, Ud, lsrc_m2e, ldst_m2e, bmlp_m2e, Wout_m2e, bout_m2e, out);

    // 8) decoder e2m
    mfma_gemm<H, 256, false, false, false, false><<<ge, blk, 0, stream>>>(
        B_e, nullptr, pW1a_e2m, nullptr, nullptr, Us, N_E);
    mfma_gemm<H, 256, false, false, false, false><<<gm, blk, 0, stream>>>(
        B_m, nullptr, pW1b_e2m, nullptr, nullptr, Ud, N_M);
    edge_decode_kernel<<<gdq, blk, 0, stream>>>(
        Us, Ud, lsrc_e2m, ldst_e2m, bmlp_e2m, Wout_e2m, bout_e2m, out + NLBL);
}

// Round 6
// 662.795 us; speedup vs baseline: 3.4702x; 3.4702x over previous
//
#include <hip/hip_runtime.h>
#include <math.h>

#define N_M 100000
#define N_E 50000
#define FM 256
#define FE 64
#define H 128
#define NEDGE 1000000
#define NLBL 250000

#define BUCK 128                       // dst nodes per bucket
#define NB_M ((N_M + BUCK - 1) / BUCK) // 782
#define NB_E ((N_E + BUCK - 1) / BUCK) // 391
#define CAP_M 2048                     // >> mean 1280 (+21 sigma)
#define CAP_E 4096                     // >> mean 2560 (+30 sigma)
#define CHUNK 8192

typedef unsigned short u16;
typedef unsigned int u32;
typedef short bf16x8 __attribute__((ext_vector_type(8)));
typedef float f32x4  __attribute__((ext_vector_type(4)));
typedef u16 u16x8    __attribute__((ext_vector_type(8)));
typedef u16 u16x4    __attribute__((ext_vector_type(4)));

__device__ __forceinline__ u16 f2bf(float x) {
    unsigned u = __float_as_uint(x);
    u += 0x7FFF + ((u >> 16) & 1);           // RNE
    return (u16)(u >> 16);
}
__device__ __forceinline__ float bf2f(u16 h) {
    return __uint_as_float(((unsigned)h) << 16);
}

// ---------------------------------------------------------------------------
// Weight packing into mfma_f32_16x16x32_bf16 B-fragment order.
// ---------------------------------------------------------------------------
#define NPACK 14
struct PackDesc { const float* src; u16* dst; int K, N; };
struct PackArgs { PackDesc d[NPACK]; };

__global__ __launch_bounds__(64)
void pack_kernel(PackArgs args)
{
    PackDesc pd = args.d[blockIdx.y];
    int KT = pd.K / 32, NT = pd.N / 16;
    int tile = blockIdx.x;
    if (tile >= KT * NT) return;
    int kt = tile / NT, nt = tile % NT;
    int l = threadIdx.x;
    u16* dst = pd.dst + ((size_t)tile * 64 + l) * 8;
    #pragma unroll
    for (int j = 0; j < 8; ++j) {
        float v = pd.src[(size_t)(kt * 32 + (l >> 4) * 8 + j) * pd.N + nt * 16 + (l & 15)];
        dst[j] = f2bf(v);
    }
}

// ---------------------------------------------------------------------------
// MFMA GEMM: C[M,N](bf16) = act( A1@W1 [+ A2@W2] [+ bias] )
// ---------------------------------------------------------------------------
template<int K, int N, bool HAS_A2, bool RELU, bool A_FP32, bool HAS_BIAS>
__global__ __launch_bounds__(256)
void mfma_gemm(const void* __restrict__ A1, const void* __restrict__ A2,
               const u16* __restrict__ W1p, const u16* __restrict__ W2p,
               const float* __restrict__ bias, u16* __restrict__ C, int M)
{
    constexpr int NT = N / 16, KT = K / 32;
    const int wid = threadIdx.x >> 6, lane = threadIdx.x & 63;
    const int row0 = blockIdx.x * 64 + wid * 16;
    if (row0 >= M) return;
    const int l15 = lane & 15, l4 = lane >> 4;

    f32x4 acc[NT];
    #pragma unroll
    for (int nt = 0; nt < NT; ++nt) acc[nt] = (f32x4){0.f, 0.f, 0.f, 0.f};

    const int npass = HAS_A2 ? 2 : 1;
    for (int pass = 0; pass < npass; ++pass) {
        const void* A = pass ? A2 : A1;
        const u16* Wp = pass ? W2p : W1p;
        #pragma unroll
        for (int kt = 0; kt < KT; ++kt) {
            bf16x8 a;
            if constexpr (A_FP32) {
                const float* ap = (const float*)A + (size_t)(row0 + l15) * K + kt * 32 + l4 * 8;
                float4 f0 = *(const float4*)ap;
                float4 f1 = *(const float4*)(ap + 4);
                a[0] = (short)f2bf(f0.x); a[1] = (short)f2bf(f0.y);
                a[2] = (short)f2bf(f0.z); a[3] = (short)f2bf(f0.w);
                a[4] = (short)f2bf(f1.x); a[5] = (short)f2bf(f1.y);
                a[6] = (short)f2bf(f1.z); a[7] = (short)f2bf(f1.w);
            } else {
                a = *(const bf16x8*)((const u16*)A + (size_t)(row0 + l15) * K + kt * 32 + l4 * 8);
            }
            #pragma unroll
            for (int nt = 0; nt < NT; ++nt) {
                bf16x8 b = *(const bf16x8*)(Wp + ((size_t)(kt * NT + nt) * 64 + lane) * 8);
                acc[nt] = __builtin_amdgcn_mfma_f32_16x16x32_bf16(a, b, acc[nt], 0, 0, 0);
            }
        }
    }

    #pragma unroll
    for (int nt = 0; nt < NT; ++nt) {
        #pragma unroll
        for (int r = 0; r < 4; ++r) {
            int row = row0 + l4 * 4 + r;
            int col = nt * 16 + l15;
            float v = acc[nt][r];
            if (HAS_BIAS) v += bias[col];
            if (RELU) v = fmaxf(v, 0.f);
            C[(size_t)row * N + col] = f2bf(v);
        }
    }
}

// ---------------------------------------------------------------------------
// Phase A: LDS-staged bucketing of edges by dst bucket. Contiguous chunk
// writes per (block,bucket) — no cacheline write amplification.
// Payload: packed u32 = (dst_local << 24) | src.
// ---------------------------------------------------------------------------
template<int NB, int CAP>
__global__ __launch_bounds__(1024)
void bucket_kernel(const int* __restrict__ src, const int* __restrict__ dst,
                   u32* __restrict__ pairs, int* __restrict__ gcur)
{
    __shared__ u32 stag[CHUNK];     // 32 KB
    __shared__ int cnt[1024];
    __shared__ int sc[1024];
    __shared__ int base[1024];
    __shared__ int cursor[1024];

    const int tid = threadIdx.x;
    const int e0 = blockIdx.x * CHUNK;
    const int e1 = min(e0 + CHUNK, NEDGE);

    cnt[tid] = 0;
    __syncthreads();
    for (int e = e0 + tid; e < e1; e += 1024)
        atomicAdd(&cnt[dst[e] >> 7], 1);            // BUCK = 128
    __syncthreads();

    int myc = cnt[tid];
    sc[tid] = myc;
    __syncthreads();
    for (int off = 1; off < 1024; off <<= 1) {
        int t = (tid >= off) ? sc[tid - off] : 0;
        __syncthreads();
        sc[tid] += t;
        __syncthreads();
    }
    int ex = sc[tid] - myc;
    base[tid] = ex;
    cursor[tid] = ex;
    __syncthreads();

    for (int e = e0 + tid; e < e1; e += 1024) {
        int d = dst[e];
        int bb = d >> 7;
        int p = atomicAdd(&cursor[bb], 1);
        stag[p] = ((u32)(d & (BUCK - 1)) << 24) | (u32)src[e];
    }
    __syncthreads();

    // copy out: wave w handles buckets w, w+16, ...
    const int wid = tid >> 6, lane = tid & 63;
    for (int bb = wid; bb < NB; bb += 16) {
        int c = cnt[bb];
        if (c == 0) continue;
        int gb = 0;
        if (lane == 0) gb = atomicAdd(&gcur[bb], c);
        gb = __shfl(gb, 0);
        int lb = base[bb];
        for (int i = lane; i < c; i += 64) {
            int idx = gb + i;
            if (idx < CAP) pairs[(size_t)bb * CAP + idx] = stag[lb + i];
        }
    }
}

// ---------------------------------------------------------------------------
// Phase B v2: per-bucket counting sort by local node (LDS), then REGISTER
// accumulation per 32-lane group — no LDS atomics on the feature path,
// small LDS footprint -> 8 blocks/CU.
// ---------------------------------------------------------------------------
template<int CAP>
__global__ __launch_bounds__(256)
void bucket_mean2_kernel(const u16* __restrict__ z,
                         const u32* __restrict__ pairs, const int* __restrict__ gcur,
                         u16* __restrict__ outm, int n_nodes)
{
    __shared__ int loc_src[CAP];            // srcs sorted by local dst
    __shared__ int cnt[BUCK], seg[BUCK], cur[BUCK];

    const int tid = threadIdx.x;
    const int b = blockIdx.x;
    const int n = min(gcur[b], CAP);
    const u32* __restrict__ pb = pairs + (size_t)b * CAP;

    if (tid < BUCK) cnt[tid] = 0;
    __syncthreads();
    for (int e = tid; e < n; e += 256)
        atomicAdd(&cnt[pb[e] >> 24], 1);
    __syncthreads();

    int myc = (tid < BUCK) ? cnt[tid] : 0;
    if (tid < BUCK) seg[tid] = myc;
    __syncthreads();
    for (int off = 1; off < BUCK; off <<= 1) {
        int t = 0;
        if (tid < BUCK && tid >= off) t = seg[tid - off];
        __syncthreads();
        if (tid < BUCK && tid >= off) seg[tid] += t;
        __syncthreads();
    }
    if (tid < BUCK) { int ex = seg[tid] - myc; seg[tid] = ex; cur[tid] = ex; }
    __syncthreads();

    for (int e = tid; e < n; e += 256) {
        u32 pk = pb[e];
        int p = atomicAdd(&cur[pk >> 24], 1);
        loc_src[p] = (int)(pk & 0xFFFFFF);
    }
    __syncthreads();

    // group g accumulates nodes g, g+8, ... in registers (2-way unrolled)
    const int grp = tid >> 5, lane = tid & 31;
    for (int loc = grp; loc < BUCK; loc += 8) {
        int gnode = b * BUCK + loc;
        if (gnode >= n_nodes) continue;
        int s0 = seg[loc], c = cnt[loc];
        float4 accA = {0.f, 0.f, 0.f, 0.f};
        float4 accB = {0.f, 0.f, 0.f, 0.f};
        int i = 0;
        for (; i + 2 <= c; i += 2) {
            int sA = loc_src[s0 + i];
            int sB = loc_src[s0 + i + 1];
            u16x4 vA = *(const u16x4*)&z[(size_t)sA * H + lane * 4];
            u16x4 vB = *(const u16x4*)&z[(size_t)sB * H + lane * 4];
            accA.x += bf2f(vA[0]); accA.y += bf2f(vA[1]);
            accA.z += bf2f(vA[2]); accA.w += bf2f(vA[3]);
            accB.x += bf2f(vB[0]); accB.y += bf2f(vB[1]);
            accB.z += bf2f(vB[2]); accB.w += bf2f(vB[3]);
        }
        if (i < c) {
            int sA = loc_src[s0 + i];
            u16x4 vA = *(const u16x4*)&z[(size_t)sA * H + lane * 4];
            accA.x += bf2f(vA[0]); accA.y += bf2f(vA[1]);
            accA.z += bf2f(vA[2]); accA.w += bf2f(vA[3]);
        }
        accA.x += accB.x; accA.y += accB.y; accA.z += accB.z; accA.w += accB.w;
        float inv = 1.0f / fmaxf((float)c, 1.0f);
        u16x4 o;
        o[0] = f2bf(accA.x * inv); o[1] = f2bf(accA.y * inv);
        o[2] = f2bf(accA.z * inv); o[3] = f2bf(accA.w * inv);
        *(u16x4*)&outm[(size_t)gnode * H + lane * 4] = o;
    }
}

// ---------------------------------------------------------------------------
// Edge decode: out[e] = sigmoid( relu(Us[s] + Ud[d] + b1) . W2 + b2 )
// ---------------------------------------------------------------------------
#define EPQ 8
#define NQ  31250   // NLBL / EPQ

__global__ __launch_bounds__(256)
void edge_decode_kernel(const u16* __restrict__ Us, const u16* __restrict__ Ud,
                        const int* __restrict__ lsrc, const int* __restrict__ ldst,
                        const float* __restrict__ b1, const float* __restrict__ W2,
                        const float* __restrict__ b2, float* __restrict__ out)
{
    const int t  = blockIdx.x * 256 + threadIdx.x;
    const int q  = t >> 4;
    const int li = t & 15;
    if (q >= NQ) return;

    float w2v[16], b1v[16];
    #pragma unroll
    for (int j = 0; j < 4; ++j) {
        float4 w = *(const float4*)&W2[li * 16 + j * 4];
        float4 bb = *(const float4*)&b1[li * 16 + j * 4];
        w2v[j*4+0] = w.x; w2v[j*4+1] = w.y; w2v[j*4+2] = w.z; w2v[j*4+3] = w.w;
        b1v[j*4+0] = bb.x; b1v[j*4+1] = bb.y; b1v[j*4+2] = bb.z; b1v[j*4+3] = bb.w;
    }
    const float bout = b2[0];

    #pragma unroll
    for (int i = 0; i < EPQ; ++i) {
        int e = q + i * NQ;
        int s = lsrc[e], d = ldst[e];
        const u16* us = Us + (size_t)s * 256 + li * 16;
        const u16* ud = Ud + (size_t)d * 256 + li * 16;
        u16x8 sa = *(const u16x8*)us;
        u16x8 sb = *(const u16x8*)(us + 8);
        u16x8 da = *(const u16x8*)ud;
        u16x8 db = *(const u16x8*)(ud + 8);
        float acc = 0.f;
        #pragma unroll
        for (int j = 0; j < 8; ++j)
            acc += fmaxf(bf2f(sa[j]) + bf2f(da[j]) + b1v[j], 0.f) * w2v[j];
        #pragma unroll
        for (int j = 0; j < 8; ++j)
            acc += fmaxf(bf2f(sb[j]) + bf2f(db[j]) + b1v[8 + j], 0.f) * w2v[8 + j];
        acc += __shfl_xor(acc, 1, 16);
        acc += __shfl_xor(acc, 2, 16);
        acc += __shfl_xor(acc, 4, 16);
        acc += __shfl_xor(acc, 8, 16);
        if (li == 0) out[e] = 1.0f / (1.0f + expf(-(acc + bout)));
    }
}

// ---------------------------------------------------------------------------
extern "C" void kernel_launch(void* const* d_in, const int* in_sizes, int n_in,
                              void* d_out, int out_size, void* d_ws, size_t ws_size,
                              hipStream_t stream)
{
    const float* x_m      = (const float*)d_in[0];
    const float* x_e      = (const float*)d_in[1];
    const int*   src_m2e  = (const int*)d_in[2];
    const int*   dst_m2e  = (const int*)d_in[3];
    const int*   src_e2m  = (const int*)d_in[4];
    const int*   dst_e2m  = (const int*)d_in[5];
    const int*   lsrc_m2e = (const int*)d_in[6];
    const int*   ldst_m2e = (const int*)d_in[7];
    const int*   lsrc_e2m = (const int*)d_in[8];
    const int*   ldst_e2m = (const int*)d_in[9];
    const float* Wp_m   = (const float*)d_in[10];
    const float* bp_m   = (const float*)d_in[11];
    const float* Wp_e   = (const float*)d_in[12];
    const float* bp_e   = (const float*)d_in[13];
    const float* Wl_m2e = (const float*)d_in[14];
    const float* bl_m2e = (const float*)d_in[15];
    const float* Wr_m2e = (const float*)d_in[16];
    const float* Wl_e2m = (const float*)d_in[17];
    const float* bl_e2m = (const float*)d_in[18];
    const float* Wr_e2m = (const float*)d_in[19];
    const float* Wffw_m = (const float*)d_in[20];
    const float* bffw_m = (const float*)d_in[21];
    const float* Wffw_e = (const float*)d_in[22];
    const float* bffw_e = (const float*)d_in[23];
    const float* Wproj_m = (const float*)d_in[24];
    const float* bproj_m = (const float*)d_in[25];
    const float* Wproj_e = (const float*)d_in[26];
    const float* bproj_e = (const float*)d_in[27];
    const float* Wmlp_m2e = (const float*)d_in[28];
    const float* bmlp_m2e = (const float*)d_in[29];
    const float* Wout_m2e = (const float*)d_in[30];
    const float* bout_m2e = (const float*)d_in[31];
    const float* Wmlp_e2m = (const float*)d_in[32];
    const float* bmlp_e2m = (const float*)d_in[33];
    const float* Wout_e2m = (const float*)d_in[34];
    const float* bout_e2m = (const float*)d_in[35];

    float* out = (float*)d_out;

    // ---- workspace layout (u16 elems unless noted) ----
    u16* B_m = (u16*)d_ws;                       // mean_m -> h_m
    u16* B_e = B_m + (size_t)N_M * H;            // mean_e -> h_e
    u16* U0  = B_e + (size_t)N_E * H;            // 2*N_M*256 u16 region
    u16* A_m = U0;                               // z_m -> h_ffw_m
    u16* A_e = A_m + (size_t)N_M * H;
    u16* Us  = U0;                               // decoder precomputes (step 7+)
    u16* Ud  = U0 + (size_t)N_M * 256;
    // pairs/gcur overlay dead tail of U region (dead before Us/Ud written)
    u32* pairs_m = (u32*)(A_e + (size_t)N_E * H);
    u32* pairs_e = pairs_m + (size_t)NB_M * CAP_M;
    int* gcur_m  = (int*)(pairs_e + (size_t)NB_E * CAP_E);
    int* gcur_e  = gcur_m + NB_M;
    u16* pk = U0 + 2 * (size_t)N_M * 256;
    u16* pWp_m   = pk;  pk += 256 * 128;
    u16* pWp_e   = pk;  pk += 64 * 128;
    u16* pWl_e2m = pk;  pk += 128 * 128;
    u16* pWr_e2m = pk;  pk += 128 * 128;
    u16* pWl_m2e = pk;  pk += 128 * 128;
    u16* pWr_m2e = pk;  pk += 128 * 128;
    u16* pWffw_m = pk;  pk += 128 * 128;
    u16* pWffw_e = pk;  pk += 128 * 128;
    u16* pWproj_m= pk;  pk += 128 * 128;
    u16* pWproj_e= pk;  pk += 128 * 128;
    u16* pW1a_m2e= pk;  pk += 128 * 256;
    u16* pW1b_m2e= pk;  pk += 128 * 256;
    u16* pW1a_e2m= pk;  pk += 128 * 256;
    u16* pW1b_e2m= pk;  pk += 128 * 256;

    dim3 blk(256);
    dim3 gm((N_M + 63) / 64), ge((N_E + 63) / 64);

    // 0) pack all weights into MFMA B-frag layout
    PackArgs pa;
    pa.d[0]  = { Wp_m,               pWp_m,    FM, H };
    pa.d[1]  = { Wp_e,               pWp_e,    FE, H };
    pa.d[2]  = { Wl_e2m,             pWl_e2m,  H,  H };
    pa.d[3]  = { Wr_e2m,             pWr_e2m,  H,  H };
    pa.d[4]  = { Wl_m2e,             pWl_m2e,  H,  H };
    pa.d[5]  = { Wr_m2e,             pWr_m2e,  H,  H };
    pa.d[6]  = { Wffw_m,             pWffw_m,  H,  H };
    pa.d[7]  = { Wffw_e,             pWffw_e,  H,  H };
    pa.d[8]  = { Wproj_m,            pWproj_m, H,  H };
    pa.d[9]  = { Wproj_e,            pWproj_e, H,  H };
    pa.d[10] = { Wmlp_m2e,           pW1a_m2e, H,  256 };
    pa.d[11] = { Wmlp_m2e + 128*256, pW1b_m2e, H,  256 };
    pa.d[12] = { Wmlp_e2m,           pW1a_e2m, H,  256 };
    pa.d[13] = { Wmlp_e2m + 128*256, pW1b_e2m, H,  256 };
    pack_kernel<<<dim3(64, NPACK), dim3(64), 0, stream>>>(pa);

    // 1) input projections (fp32 A -> bf16 out)
    mfma_gemm<FM, H, false, false, true, true><<<gm, blk, 0, stream>>>(
        x_m, nullptr, pWp_m, nullptr, bp_m, A_m, N_M);
    mfma_gemm<FE, H, false, false, true, true><<<ge, blk, 0, stream>>>(
        x_e, nullptr, pWp_e, nullptr, bp_e, A_e, N_E);

    // 2) bucket edges by destination (contiguous chunk writes)
    hipMemsetAsync(gcur_m, 0, sizeof(int) * (NB_M + NB_E), stream);
    const int nbk = (NEDGE + CHUNK - 1) / CHUNK;
    bucket_kernel<NB_M, CAP_M><<<dim3(nbk), dim3(1024), 0, stream>>>(
        src_e2m, dst_e2m, pairs_m, gcur_m);
    bucket_kernel<NB_E, CAP_E><<<dim3(nbk), dim3(1024), 0, stream>>>(
        src_m2e, dst_m2e, pairs_e, gcur_e);

    // 3) fused per-bucket sort + register-accumulated segment mean
    bucket_mean2_kernel<CAP_M><<<dim3(NB_M), blk, 0, stream>>>(
        A_e, pairs_m, gcur_m, B_m, N_M);
    bucket_mean2_kernel<CAP_E><<<dim3(NB_E), blk, 0, stream>>>(
        A_m, pairs_e, gcur_e, B_e, N_E);

    // 4) SAGE combine + relu (in place on B)
    mfma_gemm<H, H, true, true, false, true><<<gm, blk, 0, stream>>>(
        B_m, A_m, pWl_e2m, pWr_e2m, bl_e2m, B_m, N_M);
    mfma_gemm<H, H, true, true, false, true><<<ge, blk, 0, stream>>>(
        B_e, A_e, pWl_m2e, pWr_m2e, bl_m2e, B_e, N_E);

    // 5) ffw + relu: B -> A
    mfma_gemm<H, H, false, true, false, true><<<gm, blk, 0, stream>>>(
        B_m, nullptr, pWffw_m, nullptr, bffw_m, A_m, N_M);
    mfma_gemm<H, H, false, true, false, true><<<ge, blk, 0, stream>>>(
        B_e, nullptr, pWffw_e, nullptr, bffw_e, A_e, N_E);

    // 6) output projection: A -> B   (h_m in B_m, h_e in B_e)
    mfma_gemm<H, H, false, false, false, true><<<gm, blk, 0, stream>>>(
        A_m, nullptr, pWproj_m, nullptr, bproj_m, B_m, N_M);
    mfma_gemm<H, H, false, false, false, true><<<ge, blk, 0, stream>>>(
        A_e, nullptr, pWproj_e, nullptr, bproj_e, B_e, N_E);

    // 7) decoder m2e: U precompute (A/pairs region now dead) + edge decode
    dim3 gdq((NQ * 16 + 255) / 256);
    mfma_gemm<H, 256, false, false, false, false><<<gm, blk, 0, stream>>>(
        B_m, nullptr, pW1a_m2e, nullptr, nullptr, Us, N_M);
    mfma_gemm<H, 256, false, false, false, false><<<ge, blk, 0, stream>>>(
        B_e, nullptr, pW1b_m2e, nullptr, nullptr, Ud, N_E);
    edge_decode_kernel<<<gdq, blk, 0, stream>>>(
        Us, Ud, lsrc_m2e, ldst_m2e, bmlp_m2e, Wout_m2e, bout_m2e, out);

    // 8) decoder e2m
    mfma_gemm<H, 256, false, false, false, false><<<ge, blk, 0, stream>>>(
        B_e, nullptr, pW1a_e2m, nullptr, nullptr, Us, N_E);
    mfma_gemm<H, 256, false, false, false, false><<<gm, blk, 0, stream>>>(
        B_m, nullptr, pW1b_e2m, nullptr, nullptr, Ud, N_M);
    edge_decode_kernel<<<gdq, blk, 0, stream>>>(
        Us, Ud, lsrc_e2m, ldst_e2m, bmlp_e2m, Wout_e2m, bout_e2m, out + NLBL);
}

// Round 7
// 414.127 us; speedup vs baseline: 5.5539x; 1.6005x over previous
//
#include <hip/hip_runtime.h>
#include <math.h>

#define N_M 100000
#define N_E 50000
#define FM 256
#define FE 64
#define H 128
#define NEDGE 1000000
#define NLBL 250000

#define BUCK 128                       // dst nodes per bucket
#define NB_M ((N_M + BUCK - 1) / BUCK) // 782
#define NB_E ((N_E + BUCK - 1) / BUCK) // 391
#define CAP_M 2048                     // >> mean 1280 (+21 sigma)
#define CAP_E 4096                     // >> mean 2560 (+30 sigma)
#define CHUNK 8192

typedef unsigned short u16;
typedef unsigned int u32;
typedef short bf16x8 __attribute__((ext_vector_type(8)));
typedef float f32x4  __attribute__((ext_vector_type(4)));
typedef u16 u16x8    __attribute__((ext_vector_type(8)));
typedef u16 u16x4    __attribute__((ext_vector_type(4)));

__device__ __forceinline__ u16 f2bf(float x) {
    unsigned u = __float_as_uint(x);
    u += 0x7FFF + ((u >> 16) & 1);           // RNE
    return (u16)(u >> 16);
}
__device__ __forceinline__ float bf2f(u16 h) {
    return __uint_as_float(((unsigned)h) << 16);
}

// ---------------------------------------------------------------------------
// Weight packing into mfma_f32_16x16x32_bf16 B-fragment order.
// ---------------------------------------------------------------------------
#define NPACK 14
struct PackDesc { const float* src; u16* dst; int K, N; };
struct PackArgs { PackDesc d[NPACK]; };

__global__ __launch_bounds__(64)
void pack_kernel(PackArgs args)
{
    PackDesc pd = args.d[blockIdx.y];
    int KT = pd.K / 32, NT = pd.N / 16;
    int tile = blockIdx.x;
    if (tile >= KT * NT) return;
    int kt = tile / NT, nt = tile % NT;
    int l = threadIdx.x;
    u16* dst = pd.dst + ((size_t)tile * 64 + l) * 8;
    #pragma unroll
    for (int j = 0; j < 8; ++j) {
        float v = pd.src[(size_t)(kt * 32 + (l >> 4) * 8 + j) * pd.N + nt * 16 + (l & 15)];
        dst[j] = f2bf(v);
    }
}

// ---------------------------------------------------------------------------
// MFMA GEMM: C[M,N](bf16) = act( A1@W1 [+ A2@W2] [+ bias] )
// ---------------------------------------------------------------------------
template<int K, int N, bool HAS_A2, bool RELU, bool A_FP32, bool HAS_BIAS>
__global__ __launch_bounds__(256)
void mfma_gemm(const void* __restrict__ A1, const void* __restrict__ A2,
               const u16* __restrict__ W1p, const u16* __restrict__ W2p,
               const float* __restrict__ bias, u16* __restrict__ C, int M)
{
    constexpr int NT = N / 16, KT = K / 32;
    const int wid = threadIdx.x >> 6, lane = threadIdx.x & 63;
    const int row0 = blockIdx.x * 64 + wid * 16;
    if (row0 >= M) return;
    const int l15 = lane & 15, l4 = lane >> 4;

    f32x4 acc[NT];
    #pragma unroll
    for (int nt = 0; nt < NT; ++nt) acc[nt] = (f32x4){0.f, 0.f, 0.f, 0.f};

    const int npass = HAS_A2 ? 2 : 1;
    for (int pass = 0; pass < npass; ++pass) {
        const void* A = pass ? A2 : A1;
        const u16* Wp = pass ? W2p : W1p;
        #pragma unroll
        for (int kt = 0; kt < KT; ++kt) {
            bf16x8 a;
            if constexpr (A_FP32) {
                const float* ap = (const float*)A + (size_t)(row0 + l15) * K + kt * 32 + l4 * 8;
                float4 f0 = *(const float4*)ap;
                float4 f1 = *(const float4*)(ap + 4);
                a[0] = (short)f2bf(f0.x); a[1] = (short)f2bf(f0.y);
                a[2] = (short)f2bf(f0.z); a[3] = (short)f2bf(f0.w);
                a[4] = (short)f2bf(f1.x); a[5] = (short)f2bf(f1.y);
                a[6] = (short)f2bf(f1.z); a[7] = (short)f2bf(f1.w);
            } else {
                a = *(const bf16x8*)((const u16*)A + (size_t)(row0 + l15) * K + kt * 32 + l4 * 8);
            }
            #pragma unroll
            for (int nt = 0; nt < NT; ++nt) {
                bf16x8 b = *(const bf16x8*)(Wp + ((size_t)(kt * NT + nt) * 64 + lane) * 8);
                acc[nt] = __builtin_amdgcn_mfma_f32_16x16x32_bf16(a, b, acc[nt], 0, 0, 0);
            }
        }
    }

    #pragma unroll
    for (int nt = 0; nt < NT; ++nt) {
        #pragma unroll
        for (int r = 0; r < 4; ++r) {
            int row = row0 + l4 * 4 + r;
            int col = nt * 16 + l15;
            float v = acc[nt][r];
            if (HAS_BIAS) v += bias[col];
            if (RELU) v = fmaxf(v, 0.f);
            C[(size_t)row * N + col] = f2bf(v);
        }
    }
}

// ---------------------------------------------------------------------------
// Phase A v2: direct bucketing, 3 barriers, no staging/scan/serial copy-out.
// hist -> PARALLEL global reservation (one atomic per thread=bucket) ->
// direct scatter to pairs[b*CAP + gbase[b] + lds_cursor++].
// Each (block,bucket) writes a contiguous short run while its lines are L2-hot.
// Both edge directions in one launch (blockIdx.y).
// ---------------------------------------------------------------------------
__global__ __launch_bounds__(1024)
void bucket2_kernel(const int* __restrict__ src_a, const int* __restrict__ dst_a,
                    const int* __restrict__ src_b, const int* __restrict__ dst_b,
                    u32* __restrict__ pairs_a, int* __restrict__ gcur_a,
                    u32* __restrict__ pairs_b, int* __restrict__ gcur_b)
{
    __shared__ int cnt[1024];
    __shared__ int gbase[1024];

    const int dir = blockIdx.y;
    const int* __restrict__ src = dir ? src_b : src_a;
    const int* __restrict__ dst = dir ? dst_b : dst_a;
    u32* __restrict__ pairs = dir ? pairs_b : pairs_a;
    int* __restrict__ gcur  = dir ? gcur_b : gcur_a;
    const int NB  = dir ? NB_E : NB_M;
    const int CAP = dir ? CAP_E : CAP_M;

    const int tid = threadIdx.x;
    const int e0 = blockIdx.x * CHUNK;
    const int e1 = min(e0 + CHUNK, NEDGE);

    cnt[tid] = 0;
    __syncthreads();

    int myd[CHUNK / 1024];
    int k = 0;
    for (int e = e0 + tid; e < e1; e += 1024, ++k) {
        int d = dst[e];
        myd[k] = d;
        atomicAdd(&cnt[d >> 7], 1);
    }
    __syncthreads();

    if (tid < NB) {
        int c = cnt[tid];
        gbase[tid] = (c > 0) ? atomicAdd(&gcur[tid], c) : 0;
        cnt[tid] = 0;   // reuse as local cursor
    }
    __syncthreads();

    k = 0;
    for (int e = e0 + tid; e < e1; e += 1024, ++k) {
        int d = myd[k];
        int b = d >> 7;
        int p = gbase[b] + atomicAdd(&cnt[b], 1);
        if (p < CAP)
            pairs[(size_t)b * CAP + p] = ((u32)(d & (BUCK - 1)) << 24) | (u32)src[e];
    }
}

// ---------------------------------------------------------------------------
// Phase B: per-bucket counting sort by local node (LDS), then REGISTER
// accumulation per 32-lane group. Both directions in one launch.
// ---------------------------------------------------------------------------
__global__ __launch_bounds__(256)
void bucket_mean2_kernel(const u16* __restrict__ z_a, const u32* __restrict__ pairs_a,
                         const int* __restrict__ gcur_a, u16* __restrict__ out_a,
                         const u16* __restrict__ z_b, const u32* __restrict__ pairs_b,
                         const int* __restrict__ gcur_b, u16* __restrict__ out_b)
{
    __shared__ int loc_src[CAP_E];          // max(CAP_M, CAP_E) = 4096 -> 16 KB
    __shared__ int cnt[BUCK], seg[BUCK], cur[BUCK];

    const int dir = blockIdx.y;
    const int b = blockIdx.x;
    if (dir && b >= NB_E) return;

    const u16* __restrict__ z     = dir ? z_b : z_a;
    const u32* __restrict__ pairs = dir ? pairs_b : pairs_a;
    const int* __restrict__ gcur  = dir ? gcur_b : gcur_a;
    u16* __restrict__ outm        = dir ? out_b : out_a;
    const int cap     = dir ? CAP_E : CAP_M;
    const int n_nodes = dir ? N_E : N_M;

    const int tid = threadIdx.x;
    const int n = min(gcur[b], cap);
    const u32* __restrict__ pb = pairs + (size_t)b * cap;

    if (tid < BUCK) cnt[tid] = 0;
    __syncthreads();
    for (int e = tid; e < n; e += 256)
        atomicAdd(&cnt[pb[e] >> 24], 1);
    __syncthreads();

    int myc = (tid < BUCK) ? cnt[tid] : 0;
    if (tid < BUCK) seg[tid] = myc;
    __syncthreads();
    for (int off = 1; off < BUCK; off <<= 1) {
        int t = 0;
        if (tid < BUCK && tid >= off) t = seg[tid - off];
        __syncthreads();
        if (tid < BUCK && tid >= off) seg[tid] += t;
        __syncthreads();
    }
    if (tid < BUCK) { int ex = seg[tid] - myc; seg[tid] = ex; cur[tid] = ex; }
    __syncthreads();

    for (int e = tid; e < n; e += 256) {
        u32 pk = pb[e];
        int p = atomicAdd(&cur[pk >> 24], 1);
        loc_src[p] = (int)(pk & 0xFFFFFF);
    }
    __syncthreads();

    const int grp = tid >> 5, lane = tid & 31;
    for (int loc = grp; loc < BUCK; loc += 8) {
        int gnode = b * BUCK + loc;
        if (gnode >= n_nodes) continue;
        int s0 = seg[loc], c = cnt[loc];
        float4 accA = {0.f, 0.f, 0.f, 0.f};
        float4 accB = {0.f, 0.f, 0.f, 0.f};
        int i = 0;
        for (; i + 2 <= c; i += 2) {
            int sA = loc_src[s0 + i];
            int sB = loc_src[s0 + i + 1];
            u16x4 vA = *(const u16x4*)&z[(size_t)sA * H + lane * 4];
            u16x4 vB = *(const u16x4*)&z[(size_t)sB * H + lane * 4];
            accA.x += bf2f(vA[0]); accA.y += bf2f(vA[1]);
            accA.z += bf2f(vA[2]); accA.w += bf2f(vA[3]);
            accB.x += bf2f(vB[0]); accB.y += bf2f(vB[1]);
            accB.z += bf2f(vB[2]); accB.w += bf2f(vB[3]);
        }
        if (i < c) {
            int sA = loc_src[s0 + i];
            u16x4 vA = *(const u16x4*)&z[(size_t)sA * H + lane * 4];
            accA.x += bf2f(vA[0]); accA.y += bf2f(vA[1]);
            accA.z += bf2f(vA[2]); accA.w += bf2f(vA[3]);
        }
        accA.x += accB.x; accA.y += accB.y; accA.z += accB.z; accA.w += accB.w;
        float inv = 1.0f / fmaxf((float)c, 1.0f);
        u16x4 o;
        o[0] = f2bf(accA.x * inv); o[1] = f2bf(accA.y * inv);
        o[2] = f2bf(accA.z * inv); o[3] = f2bf(accA.w * inv);
        *(u16x4*)&outm[(size_t)gnode * H + lane * 4] = o;
    }
}

// ---------------------------------------------------------------------------
// Edge decode: out[e] = sigmoid( relu(Us[s] + Ud[d] + b1) . W2 + b2 )
// ---------------------------------------------------------------------------
#define EPQ 8
#define NQ  31250   // NLBL / EPQ

__global__ __launch_bounds__(256)
void edge_decode_kernel(const u16* __restrict__ Us, const u16* __restrict__ Ud,
                        const int* __restrict__ lsrc, const int* __restrict__ ldst,
                        const float* __restrict__ b1, const float* __restrict__ W2,
                        const float* __restrict__ b2, float* __restrict__ out)
{
    const int t  = blockIdx.x * 256 + threadIdx.x;
    const int q  = t >> 4;
    const int li = t & 15;
    if (q >= NQ) return;

    float w2v[16], b1v[16];
    #pragma unroll
    for (int j = 0; j < 4; ++j) {
        float4 w = *(const float4*)&W2[li * 16 + j * 4];
        float4 bb = *(const float4*)&b1[li * 16 + j * 4];
        w2v[j*4+0] = w.x; w2v[j*4+1] = w.y; w2v[j*4+2] = w.z; w2v[j*4+3] = w.w;
        b1v[j*4+0] = bb.x; b1v[j*4+1] = bb.y; b1v[j*4+2] = bb.z; b1v[j*4+3] = bb.w;
    }
    const float bout = b2[0];

    #pragma unroll
    for (int i = 0; i < EPQ; ++i) {
        int e = q + i * NQ;
        int s = lsrc[e], d = ldst[e];
        const u16* us = Us + (size_t)s * 256 + li * 16;
        const u16* ud = Ud + (size_t)d * 256 + li * 16;
        u16x8 sa = *(const u16x8*)us;
        u16x8 sb = *(const u16x8*)(us + 8);
        u16x8 da = *(const u16x8*)ud;
        u16x8 db = *(const u16x8*)(ud + 8);
        float acc = 0.f;
        #pragma unroll
        for (int j = 0; j < 8; ++j)
            acc += fmaxf(bf2f(sa[j]) + bf2f(da[j]) + b1v[j], 0.f) * w2v[j];
        #pragma unroll
        for (int j = 0; j < 8; ++j)
            acc += fmaxf(bf2f(sb[j]) + bf2f(db[j]) + b1v[8 + j], 0.f) * w2v[8 + j];
        acc += __shfl_xor(acc, 1, 16);
        acc += __shfl_xor(acc, 2, 16);
        acc += __shfl_xor(acc, 4, 16);
        acc += __shfl_xor(acc, 8, 16);
        if (li == 0) out[e] = 1.0f / (1.0f + expf(-(acc + bout)));
    }
}

// ---------------------------------------------------------------------------
extern "C" void kernel_launch(void* const* d_in, const int* in_sizes, int n_in,
                              void* d_out, int out_size, void* d_ws, size_t ws_size,
                              hipStream_t stream)
{
    const float* x_m      = (const float*)d_in[0];
    const float* x_e      = (const float*)d_in[1];
    const int*   src_m2e  = (const int*)d_in[2];
    const int*   dst_m2e  = (const int*)d_in[3];
    const int*   src_e2m  = (const int*)d_in[4];
    const int*   dst_e2m  = (const int*)d_in[5];
    const int*   lsrc_m2e = (const int*)d_in[6];
    const int*   ldst_m2e = (const int*)d_in[7];
    const int*   lsrc_e2m = (const int*)d_in[8];
    const int*   ldst_e2m = (const int*)d_in[9];
    const float* Wp_m   = (const float*)d_in[10];
    const float* bp_m   = (const float*)d_in[11];
    const float* Wp_e   = (const float*)d_in[12];
    const float* bp_e   = (const float*)d_in[13];
    const float* Wl_m2e = (const float*)d_in[14];
    const float* bl_m2e = (const float*)d_in[15];
    const float* Wr_m2e = (const float*)d_in[16];
    const float* Wl_e2m = (const float*)d_in[17];
    const float* bl_e2m = (const float*)d_in[18];
    const float* Wr_e2m = (const float*)d_in[19];
    const float* Wffw_m = (const float*)d_in[20];
    const float* bffw_m = (const float*)d_in[21];
    const float* Wffw_e = (const float*)d_in[22];
    const float* bffw_e = (const float*)d_in[23];
    const float* Wproj_m = (const float*)d_in[24];
    const float* bproj_m = (const float*)d_in[25];
    const float* Wproj_e = (const float*)d_in[26];
    const float* bproj_e = (const float*)d_in[27];
    const float* Wmlp_m2e = (const float*)d_in[28];
    const float* bmlp_m2e = (const float*)d_in[29];
    const float* Wout_m2e = (const float*)d_in[30];
    const float* bout_m2e = (const float*)d_in[31];
    const float* Wmlp_e2m = (const float*)d_in[32];
    const float* bmlp_e2m = (const float*)d_in[33];
    const float* Wout_e2m = (const float*)d_in[34];
    const float* bout_e2m = (const float*)d_in[35];

    float* out = (float*)d_out;

    // ---- workspace layout (u16 elems unless noted) ----
    u16* B_m = (u16*)d_ws;                       // mean_m -> h_m
    u16* B_e = B_m + (size_t)N_M * H;            // mean_e -> h_e
    u16* U0  = B_e + (size_t)N_E * H;            // 2*N_M*256 u16 region
    u16* A_m = U0;                               // z_m -> h_ffw_m
    u16* A_e = A_m + (size_t)N_M * H;
    u16* Us  = U0;                               // decoder precomputes (step 7+)
    u16* Ud  = U0 + (size_t)N_M * 256;
    // pairs/gcur overlay dead tail of U region (dead before Us/Ud written)
    u32* pairs_m = (u32*)(A_e + (size_t)N_E * H);
    u32* pairs_e = pairs_m + (size_t)NB_M * CAP_M;
    int* gcur_m  = (int*)(pairs_e + (size_t)NB_E * CAP_E);
    int* gcur_e  = gcur_m + NB_M;
    u16* pk = U0 + 2 * (size_t)N_M * 256;
    u16* pWp_m   = pk;  pk += 256 * 128;
    u16* pWp_e   = pk;  pk += 64 * 128;
    u16* pWl_e2m = pk;  pk += 128 * 128;
    u16* pWr_e2m = pk;  pk += 128 * 128;
    u16* pWl_m2e = pk;  pk += 128 * 128;
    u16* pWr_m2e = pk;  pk += 128 * 128;
    u16* pWffw_m = pk;  pk += 128 * 128;
    u16* pWffw_e = pk;  pk += 128 * 128;
    u16* pWproj_m= pk;  pk += 128 * 128;
    u16* pWproj_e= pk;  pk += 128 * 128;
    u16* pW1a_m2e= pk;  pk += 128 * 256;
    u16* pW1b_m2e= pk;  pk += 128 * 256;
    u16* pW1a_e2m= pk;  pk += 128 * 256;
    u16* pW1b_e2m= pk;  pk += 128 * 256;

    dim3 blk(256);
    dim3 gm((N_M + 63) / 64), ge((N_E + 63) / 64);

    // 0) pack all weights into MFMA B-frag layout
    PackArgs pa;
    pa.d[0]  = { Wp_m,               pWp_m,    FM, H };
    pa.d[1]  = { Wp_e,               pWp_e,    FE, H };
    pa.d[2]  = { Wl_e2m,             pWl_e2m,  H,  H };
    pa.d[3]  = { Wr_e2m,             pWr_e2m,  H,  H };
    pa.d[4]  = { Wl_m2e,             pWl_m2e,  H,  H };
    pa.d[5]  = { Wr_m2e,             pWr_m2e,  H,  H };
    pa.d[6]  = { Wffw_m,             pWffw_m,  H,  H };
    pa.d[7]  = { Wffw_e,             pWffw_e,  H,  H };
    pa.d[8]  = { Wproj_m,            pWproj_m, H,  H };
    pa.d[9]  = { Wproj_e,            pWproj_e, H,  H };
    pa.d[10] = { Wmlp_m2e,           pW1a_m2e, H,  256 };
    pa.d[11] = { Wmlp_m2e + 128*256, pW1b_m2e, H,  256 };
    pa.d[12] = { Wmlp_e2m,           pW1a_e2m, H,  256 };
    pa.d[13] = { Wmlp_e2m + 128*256, pW1b_e2m, H,  256 };
    pack_kernel<<<dim3(64, NPACK), dim3(64), 0, stream>>>(pa);

    // 1) input projections (fp32 A -> bf16 out)
    mfma_gemm<FM, H, false, false, true, true><<<gm, blk, 0, stream>>>(
        x_m, nullptr, pWp_m, nullptr, bp_m, A_m, N_M);
    mfma_gemm<FE, H, false, false, true, true><<<ge, blk, 0, stream>>>(
        x_e, nullptr, pWp_e, nullptr, bp_e, A_e, N_E);

    // 2) bucket edges by destination, both directions in one launch
    hipMemsetAsync(gcur_m, 0, sizeof(int) * (NB_M + NB_E), stream);
    const int nbk = (NEDGE + CHUNK - 1) / CHUNK;
    bucket2_kernel<<<dim3(nbk, 2), dim3(1024), 0, stream>>>(
        src_e2m, dst_e2m, src_m2e, dst_m2e,
        pairs_m, gcur_m, pairs_e, gcur_e);

    // 3) fused per-bucket sort + register-accumulated segment mean (both dirs)
    bucket_mean2_kernel<<<dim3(NB_M, 2), blk, 0, stream>>>(
        A_e, pairs_m, gcur_m, B_m,
        A_m, pairs_e, gcur_e, B_e);

    // 4) SAGE combine + relu (in place on B)
    mfma_gemm<H, H, true, true, false, true><<<gm, blk, 0, stream>>>(
        B_m, A_m, pWl_e2m, pWr_e2m, bl_e2m, B_m, N_M);
    mfma_gemm<H, H, true, true, false, true><<<ge, blk, 0, stream>>>(
        B_e, A_e, pWl_m2e, pWr_m2e, bl_m2e, B_e, N_E);

    // 5) ffw + relu: B -> A
    mfma_gemm<H, H, false, true, false, true><<<gm, blk, 0, stream>>>(
        B_m, nullptr, pWffw_m, nullptr, bffw_m, A_m, N_M);
    mfma_gemm<H, H, false, true, false, true><<<ge, blk, 0, stream>>>(
        B_e, nullptr, pWffw_e, nullptr, bffw_e, A_e, N_E);

    // 6) output projection: A -> B   (h_m in B_m, h_e in B_e)
    mfma_gemm<H, H, false, false, false, true><<<gm, blk, 0, stream>>>(
        A_m, nullptr, pWproj_m, nullptr, bproj_m, B_m, N_M);
    mfma_gemm<H, H, false, false, false, true><<<ge, blk, 0, stream>>>(
        A_e, nullptr, pWproj_e, nullptr, bproj_e, B_e, N_E);

    // 7) decoder m2e: U precompute (A/pairs region now dead) + edge decode
    dim3 gdq((NQ * 16 + 255) / 256);
    mfma_gemm<H, 256, false, false, false, false><<<gm, blk, 0, stream>>>(
        B_m, nullptr, pW1a_m2e, nullptr, nullptr, Us, N_M);
    mfma_gemm<H, 256, false, false, false, false><<<ge, blk, 0, stream>>>(
        B_e, nullptr, pW1b_m2e, nullptr, nullptr, Ud, N_E);
    edge_decode_kernel<<<gdq, blk, 0, stream>>>(
        Us, Ud, lsrc_m2e, ldst_m2e, bmlp_m2e, Wout_m2e, bout_m2e, out);

    // 8) decoder e2m
    mfma_gemm<H, 256, false, false, false, false><<<ge, blk, 0, stream>>>(
        B_e, nullptr, pW1a_e2m, nullptr, nullptr, Us, N_E);
    mfma_gemm<H, 256, false, false, false, false><<<gm, blk, 0, stream>>>(
        B_m, nullptr, pW1b_e2m, nullptr, nullptr, Ud, N_M);
    edge_decode_kernel<<<gdq, blk, 0, stream>>>(
        Us, Ud, lsrc_e2m, ldst_e2m, bmlp_e2m, Wout_e2m, bout_e2m, out + NLBL);
}